// Round 11
// baseline (104.704 us; speedup 1.0000x reference)
//
#include <hip/hip_runtime.h>
#include <hip/hip_bf16.h>

#define B_    32
#define C_    128
#define L_    4096
#define P_    100
#define NPT   7            // p-tiles of 16 (P padded to 112)
#define Q_    20
#define NBIN  21
#define HSTR  37           // R7: padded hist row stride: collision only at Δnn=±13
#define NCH   (NPT * 4)    // 28 A-frag chunks; chunk = pt*4 + ks
#define CHS   512          // shorts per chunk = 64 lanes * 8 bf16 (1 KB)
#define TPB   512          // R9: 8-wave blocks, wave owns 64 l-columns
#define LSPAN 512          // l-columns per block (unchanged); grid (8,32) = 1 block/CU

typedef short          bf16x8 __attribute__((ext_vector_type(8)));
typedef float          f32x4  __attribute__((ext_vector_type(4)));
typedef unsigned short u16x8  __attribute__((ext_vector_type(8)));

__device__ inline unsigned short f2bf(float f) {
    __hip_bfloat16 h = __float2bfloat16(f);   // RNE
    unsigned short u; __builtin_memcpy(&u, &h, 2);
    return u;
}

// ---- prep: W (fp32 [P][C]) -> bf16 fragment lane order in d_ws ----
// Wf[chunk][lane][j], chunk=pt*4+ks: value = W[pt*16 + (lane&15)][ks*32 + (lane>>4)*8 + j]
// (rows p>=100 zeroed). Main kernel copies with plain dwordx4 -> conflict-free
// ds_read_b128 fragments.
__global__ void prep_w_kernel(const float* __restrict__ W, unsigned short* __restrict__ Wf) {
    const int t = blockIdx.x * 256 + threadIdx.x;     // 0 .. NCH*64-1
    if (t >= NCH * 64) return;
    const int chunk = t >> 6, lane = t & 63;
    const int pt = chunk >> 2, ks = chunk & 3;
    const int p  = pt * 16 + (lane & 15);
    const int c0 = ks * 32 + (lane >> 4) * 8;
    u16x8 v;
#pragma unroll
    for (int j = 0; j < 8; ++j)
        v[j] = (p < P_) ? f2bf(W[p * C_ + c0 + j]) : (unsigned short)0;
    *(u16x8*)(Wf + (size_t)t * 8) = v;                // 16B coalesced store
}

// ---- main: block = (b, 512-l span), 8 waves; wave owns 64 l ----
// D[p][l] = sum_c W[p][c] * X[b][c][l] via mfma_f32_16x16x32_bf16.
//
// R9 change: FLOAT4 (dwordx4) X LOADS via 4-WAY l-INTERLEAVE. Evidence chain:
// R6's full compute/load interleave was NEUTRAL (tail already hides under the
// stream) => stream itself is ~16 us; per-CU VMEM issue count matches that
// (32768 dwordx2 ~ 13.6 us at ~1 VMEM/cyc/CU); R8's gain tracked instruction
// count not bytes; the 6.3 TB/s ceiling (m13) is a float4-per-lane copy.
// So: lane nn loads float4 at l0+4*nn; tile t (t=0..3) = columns {l0+4i+t},
// component t of load j is exactly A_t[nn][k=quad*8+j]. 16384 dwordx4/CU
// (was 32768 dwordx2), bytes unchanged. Wave owns 64 columns -> acc[7][4]
// (112 VGPR) + double-buffered xf (64) needs the 256-VGPR budget:
// __launch_bounds__(512,2) = 8-wave blocks, 1 block/CU (LDS 43.6 KB).
// ks-outer prefetch-1 loop is the R6-proven spill-free shape, static indices
// only (R3/R5 lesson). Histogram is l-INDEPENDENT -> bucketing/epilogue
// unchanged; same 896 atomic instr/CU. Identical value multiset => identical
// absmax.
//
// R7 (kept): hist stride 37 + two-step prefix epilogue. R2 (kept): swapped
// MFMA operands -> D col=p(nn); algebra per tile t:
//   A_t[m][k]=X[ks*32+k][l0+4m+t], B[k][n]=W[pt*16+n][ks*32+k]
//   => D_t[m][n] = a[b, p=pt*16+n, l=l0+4m+t]   (m89-verified C/D mapping)
//
// PHASE ORDER (kept): the ONLY pre-epilogue barrier happens BEFORE any X load.
// Histogram: 21 uniform bins, prefix epilogue, exact fp32 atomicAdd
// (counts <= 512, multiples of 2^-12 -> exact).
__global__ __launch_bounds__(TPB, 2)
void radon_mfma10_kernel(const float* __restrict__ X, const unsigned short* __restrict__ Wf,
                         const float* __restrict__ minv, const float* __restrict__ maxv,
                         float* __restrict__ out) {
    __shared__ unsigned short Wlds[NCH * CHS];   // 28.0 KB
    __shared__ int   hist[P_ * HSTR];            // 14.8 KB (stride-37 rows)
    __shared__ float mn_s[P_], invd_s[P_];       // 0.8 KB

    const int tid  = threadIdx.x;
    const int b    = blockIdx.y;
    const int lblk = blockIdx.x;       // 0..7
    const int wave = tid >> 6;         // 0..7
    const int lane = tid & 63;
    const int quad = lane >> 4;
    const int nn   = lane & 15;

    // ---- Phase A: Wf -> LDS (plain dwordx4 copy), thresholds, hist zero, barrier.
    {
        const int4* src = (const int4*)Wf;
        int4* dst = (int4*)Wlds;
        for (int k = tid; k < NCH * 64; k += TPB)    // 1792 int4, L2-resident
            dst[k] = src[k];
    }
    for (int i = tid; i < P_; i += TPB) {
        const float mn = minv[i];
        mn_s[i]   = mn;
        invd_s[i] = (float)NBIN / (maxv[i] - mn);
    }
    for (int i = tid; i < P_ * HSTR; i += TPB) hist[i] = 0;
    __syncthreads();   // the ONLY barrier before the bucket epilogue

    // ---- Phase B+C fused: ks-outer stream with float4 loads (prefetch-1).
    const int l0 = lblk * LSPAN + wave * 64;
    const float* Xb = X + (size_t)b * C_ * L_ + l0 + 4 * nn;

    f32x4 acc[NPT][4];
#pragma unroll
    for (int pt = 0; pt < NPT; ++pt)
#pragma unroll
        for (int t = 0; t < 4; ++t)
            acc[pt][t] = (f32x4){0.f, 0.f, 0.f, 0.f};

    float4 xf[2][8];   // double buffer; all indices static after full unroll
#pragma unroll
    for (int j = 0; j < 8; ++j)
        xf[0][j] = *(const float4*)(Xb + (size_t)(quad * 8 + j) * L_);

#pragma unroll
    for (int ks = 0; ks < 4; ++ks) {
        __builtin_amdgcn_sched_barrier(0);   // fence: no cross-stage load hoisting
        const int cur = ks & 1, nxt = cur ^ 1;
        if (ks < 3) {
#pragma unroll
            for (int j = 0; j < 8; ++j)
                xf[nxt][j] = *(const float4*)(Xb + (size_t)((ks + 1) * 32 + quad * 8 + j) * L_);
        }
        // cvt current slice: component t of load j -> bt[t][j]
        bf16x8 bt[4];
#pragma unroll
        for (int t = 0; t < 4; ++t) {
            unsigned int u[4];
#pragma unroll
            for (int jp = 0; jp < 4; ++jp) {
                const float lo = ((const float*)&xf[cur][2 * jp])[t];
                const float hi = ((const float*)&xf[cur][2 * jp + 1])[t];
                __hip_bfloat162 h2 = __float22bfloat162_rn(make_float2(lo, hi));
                __builtin_memcpy(&u[jp], &h2, 4);
            }
            __builtin_memcpy(&bt[t], u, 16);
        }
        // 7 p-tiles: one afrag ds_read + 4 MFMA (one per tile)
#pragma unroll
        for (int pt = 0; pt < NPT; ++pt) {
            bf16x8 a = *(const bf16x8*)(&Wlds[((pt * 4 + ks) * 64 + lane) * 8]);
#pragma unroll
            for (int t = 0; t < 4; ++t)
                acc[pt][t] = __builtin_amdgcn_mfma_f32_16x16x32_bf16(bt[t], a, acc[pt][t], 0, 0, 0);
        }
    }

    // ---- bucket epilogue: p = pt*16 + nn is per-thread constant per pt.
#pragma unroll
    for (int pt = 0; pt < NPT; ++pt) {
        const int p = pt * 16 + nn;
        if (p < P_) {
            const float mn = mn_s[p], invd = invd_s[p];
            int* __restrict__ hrow = &hist[p * HSTR];
#pragma unroll
            for (int t = 0; t < 4; ++t)
#pragma unroll
                for (int r = 0; r < 4; ++r) {
                    const float tt = (acc[pt][t][r] - mn) * invd;
                    int k = 0;
                    if (tt > 0.f) { const int ki = (int)tt; k = (ki > 20) ? 20 : ki; }
                    atomicAdd(&hrow[k], 1);
                }
        }
    }
    __syncthreads();

    // ---- Phase D step 1: in-place prefix per p (one thread per row)
    if (tid < P_) {
        int* row = &hist[tid * HSTR];
        int run = 0;
#pragma unroll
        for (int k = 0; k < NBIN; ++k) { run += row[k]; row[k] = run; }
    }
    __syncthreads();

    // ---- Phase D step 2: one LDS read per output -> exact fp32 atomic accumulation
    for (int i = tid; i < P_ * Q_; i += TPB) {
        const int p  = i / Q_;
        const int qi = i - p * Q_;
        const int s  = hist[p * HSTR + qi];   // prefix over bins 0..qi
        atomicAdd(&out[((size_t)b * P_ + p) * Q_ + qi], (float)s * (1.0f / (float)L_));
    }
}

extern "C" void kernel_launch(void* const* d_in, const int* in_sizes, int n_in,
                              void* d_out, int out_size, void* d_ws, size_t ws_size,
                              hipStream_t stream) {
    const float* X  = (const float*)d_in[0];
    const float* W  = (const float*)d_in[1];
    const float* mn = (const float*)d_in[2];
    const float* mx = (const float*)d_in[3];
    float* out = (float*)d_out;
    unsigned short* Wf = (unsigned short*)d_ws;   // needs NCH*64*16 = 28672 bytes

    hipMemsetAsync(out, 0, (size_t)out_size * sizeof(float), stream);
    prep_w_kernel<<<NCH * 64 / 256, 256, 0, stream>>>(W, Wf);

    dim3 grid(L_ / LSPAN, B_);
    radon_mfma10_kernel<<<grid, dim3(TPB), 0, stream>>>(X, Wf, mn, mx, out);
}